// Round 9
// baseline (3830.324 us; speedup 1.0000x reference)
//
#include <hip/hip_runtime.h>
#include <cstdint>
#include <cstddef>

#define ALPHA 1.702f
#define LIMIT 7.0f

#define NTOK 2048
#define HDIM 2048
#define IDIM 2048
#define I2   4096
#define NEXP 8

typedef float f32x4 __attribute__((ext_vector_type(4)));
typedef short bf16x8 __attribute__((ext_vector_type(8)));
typedef unsigned short u16;

__device__ __forceinline__ u16 f2bf(float f) {
  unsigned u = __float_as_uint(f);
  u += 0x7fffu + ((u >> 16) & 1u);   // RNE
  return (u16)(u >> 16);
}

__device__ __forceinline__ void gload_lds16(const void* g, void* l) {
  __builtin_amdgcn_global_load_lds(
      (const __attribute__((address_space(1))) void*)g,
      (__attribute__((address_space(3))) void*)l, 16, 0, 0);
}

#define BARRIER() do { asm volatile("" ::: "memory"); __builtin_amdgcn_s_barrier(); asm volatile("" ::: "memory"); } while (0)
#define VMCNT(n)  asm volatile("s_waitcnt vmcnt(" #n ")" ::: "memory")

// ---------------- x: fp32 -> bf16 ----------------
__global__ __launch_bounds__(256) void k_cvt(const float* __restrict__ in,
                                             u16* __restrict__ out) {
  int i = blockIdx.x * blockDim.x + threadIdx.x;
  const float4* p = (const float4*)in + (size_t)i * 2;
  float4 a = p[0], b = p[1];
  union { u16 s[8]; uint4 v; } o;
  o.s[0] = f2bf(a.x); o.s[1] = f2bf(a.y); o.s[2] = f2bf(a.z); o.s[3] = f2bf(a.w);
  o.s[4] = f2bf(b.x); o.s[5] = f2bf(b.y); o.s[6] = f2bf(b.z); o.s[7] = f2bf(b.w);
  ((uint4*)out)[i] = o.v;
}

// ------------- transpose + convert: (R,C) fp32 -> (C,R) bf16 (verified 32x32) -------------
__global__ __launch_bounds__(256) void k_tc(const float* __restrict__ in,
                                            u16* __restrict__ out, int R, int C) {
  __shared__ float tile[32][33];
  const size_t mo = (size_t)blockIdx.z * R * C;
  const float* ip = in + mo;
  u16* op = out + mo;
  int c0 = blockIdx.x * 32, r0 = blockIdx.y * 32;
  int t = threadIdx.x;
  int tr = t >> 3, tc = (t & 7) * 4;
  float4 v = *(const float4*)&ip[(size_t)(r0 + tr) * C + c0 + tc];
  tile[tr][tc] = v.x; tile[tr][tc + 1] = v.y;
  tile[tr][tc + 2] = v.z; tile[tr][tc + 3] = v.w;
  __syncthreads();
  ushort4 o;
  o.x = f2bf(tile[tc + 0][tr]);
  o.y = f2bf(tile[tc + 1][tr]);
  o.z = f2bf(tile[tc + 2][tr]);
  o.w = f2bf(tile[tc + 3][tr]);
  *(ushort4*)&op[(size_t)(c0 + tr) * R + r0 + tc] = o;
}

// ========== 256x256 8-wave GEMM core: BK=32, 64KB LDS, 2 blocks/CU, 1 barrier/K-tile ==========
// LDS regions: Als[2][256*32], Bls[2][256*32] (16KB each region; 64KB total).
// Row = 32 bf16 = 64B = 4 slots of 16B. Swizzle: LDS[r][slot s] holds global k-slot
// s ^ ((r>>1)&3)  (involution; 2 rows share a slot pattern -> 2-way = free).

// ---------------- GEMM1: gate_up + activation + rw fold ----------------
__global__ __launch_bounds__(512, 4) void k_gemm1(const u16* __restrict__ xbf,
                                                  const u16* __restrict__ w1t,
                                                  const float* __restrict__ gub,
                                                  const float* __restrict__ rw,
                                                  u16* __restrict__ inter) {
  __shared__ __align__(16) u16 Als[2][256 * 32];
  __shared__ __align__(16) u16 Bls[2][256 * 32];

  const int bid = (int)blockIdx.x;
  const int L = (bid & 7) * 128 + (bid >> 3);
  const int mtile = L & 7, ntile = (L >> 3) & 15, e = L >> 7;
  const int row0 = mtile * 256, col0 = ntile * 256;
  const u16* A = xbf;
  const u16* B = w1t + (size_t)e * I2 * HDIM;

  const int tid = threadIdx.x;
  const int w = tid >> 6, lane = tid & 63;
  const int wr = w >> 2, wc = w & 3;
  const int rrow = lane & 15, klane = lane >> 4;
  const int kofs = ((klane ^ ((rrow >> 1) & 3)) << 3);

  // staging: thread chunks c = (w*2+j)*64 + lane; r=c>>2 (row), g=c&3 (slot)
  auto stA = [&](int buf, int k0) {
#pragma unroll
    for (int j = 0; j < 2; ++j) {
      int c = (w * 2 + j) * 64 + lane;
      int r = c >> 2, g = c & 3;
      int ks = ((g ^ ((r >> 1) & 3)) << 3);
      gload_lds16(A + (size_t)(row0 + r) * HDIM + k0 + ks,
                  &Als[buf][(size_t)(w * 2 + j) * 512]);
    }
  };
  auto stB = [&](int buf, int k0) {
#pragma unroll
    for (int j = 0; j < 2; ++j) {
      int c = (w * 2 + j) * 64 + lane;
      int r = c >> 2, g = c & 3;
      int ks = ((g ^ ((r >> 1) & 3)) << 3);
      gload_lds16(B + (size_t)(col0 + r) * HDIM + k0 + ks,
                  &Bls[buf][(size_t)(w * 2 + j) * 512]);
    }
  };

  f32x4 acc[8][4];
#pragma unroll
  for (int i = 0; i < 8; ++i)
#pragma unroll
    for (int j = 0; j < 4; ++j) acc[i][j] = (f32x4){0.f, 0.f, 0.f, 0.f};

  // prologue: tile 0 -> buf 0
  stA(0, 0); stB(0, 0);
  VMCNT(0);
  BARRIER();

  for (int t = 0; t < 64; ++t) {
    const int c = t & 1;
    const int kN = (t + 1 < 64 ? t + 1 : 63) * 32;
    // stage next tile into the other buffer (its readers finished last iter)
    stA(c ^ 1, kN); stB(c ^ 1, kN);

    bf16x8 a[8], bfr[4];
#pragma unroll
    for (int m = 0; m < 8; ++m)
      a[m] = *(const bf16x8*)&Als[c][(wr * 128 + m * 16 + rrow) * 32 + kofs];
#pragma unroll
    for (int n = 0; n < 4; ++n)
      bfr[n] = *(const bf16x8*)&Bls[c][(wc * 64 + n * 16 + rrow) * 32 + kofs];

    __builtin_amdgcn_s_setprio(1);
#pragma unroll
    for (int m = 0; m < 8; ++m)
#pragma unroll
      for (int n = 0; n < 4; ++n)
        acc[m][n] = __builtin_amdgcn_mfma_f32_16x16x32_bf16(a[m], bfr[n], acc[m][n], 0, 0, 0);
    __builtin_amdgcn_s_setprio(0);

    VMCNT(0);       // next tile fully staged (stall filled by co-resident block)
    BARRIER();
  }

  const float* bias = gub + (size_t)e * I2;
  u16* ip = inter + (size_t)e * NTOK * IDIM;
#pragma unroll
  for (int m = 0; m < 8; ++m) {
#pragma unroll
    for (int n = 0; n < 4; ++n) {
      const int col = col0 + wc * 64 + n * 16 + rrow;
      const float bv = bias[col];
#pragma unroll
      for (int r = 0; r < 4; ++r) {
        const int row = row0 + wr * 128 + m * 16 + klane * 4 + r;
        float gu = acc[m][n][r] + bv;
        float pg = __shfl_xor(gu, 1);
        float gate = (lane & 1) ? pg : gu;
        float up   = (lane & 1) ? gu : pg;
        gate = fminf(gate, LIMIT);
        up = fminf(fmaxf(up, -LIMIT), LIMIT);
        float glu = gate / (1.f + __expf(-ALPHA * gate));
        float val = (up + 1.f) * glu * rw[row * NEXP + e];
        if (!(lane & 1)) ip[(size_t)row * IDIM + (col >> 1)] = f2bf(val);
      }
    }
  }
}

// ---------------- GEMM2: split-K=8 (1 expert per split), grid 512 = 2 blocks/CU ----------------
__global__ __launch_bounds__(512, 4) void k_gemm2(const u16* __restrict__ inter,
                                                  const u16* __restrict__ w2t,
                                                  float* __restrict__ part) {
  __shared__ __align__(16) u16 Als[2][256 * 32];
  __shared__ __align__(16) u16 Bls[2][256 * 32];

  const int bid = (int)blockIdx.x;
  const int L = (bid & 7) * 64 + (bid >> 3);
  const int mtile = L & 7, ntile = (L >> 3) & 7, sp = L >> 6;  // sp = expert; 1 expert per XCD
  const int row0 = mtile * 256, col0 = ntile * 256;
  const u16* A = inter + (size_t)sp * NTOK * IDIM;
  const u16* B = w2t + (size_t)sp * HDIM * IDIM;

  const int tid = threadIdx.x;
  const int w = tid >> 6, lane = tid & 63;
  const int wr = w >> 2, wc = w & 3;
  const int rrow = lane & 15, klane = lane >> 4;
  const int kofs = ((klane ^ ((rrow >> 1) & 3)) << 3);

  auto stA = [&](int buf, int k0) {
#pragma unroll
    for (int j = 0; j < 2; ++j) {
      int c = (w * 2 + j) * 64 + lane;
      int r = c >> 2, g = c & 3;
      int ks = ((g ^ ((r >> 1) & 3)) << 3);
      gload_lds16(A + (size_t)(row0 + r) * IDIM + k0 + ks,
                  &Als[buf][(size_t)(w * 2 + j) * 512]);
    }
  };
  auto stB = [&](int buf, int k0) {
#pragma unroll
    for (int j = 0; j < 2; ++j) {
      int c = (w * 2 + j) * 64 + lane;
      int r = c >> 2, g = c & 3;
      int ks = ((g ^ ((r >> 1) & 3)) << 3);
      gload_lds16(B + (size_t)(col0 + r) * IDIM + k0 + ks,
                  &Bls[buf][(size_t)(w * 2 + j) * 512]);
    }
  };

  f32x4 acc[8][4];
#pragma unroll
  for (int i = 0; i < 8; ++i)
#pragma unroll
    for (int j = 0; j < 4; ++j) acc[i][j] = (f32x4){0.f, 0.f, 0.f, 0.f};

  stA(0, 0); stB(0, 0);
  VMCNT(0);
  BARRIER();

  for (int t = 0; t < 64; ++t) {
    const int c = t & 1;
    const int kN = (t + 1 < 64 ? t + 1 : 63) * 32;
    stA(c ^ 1, kN); stB(c ^ 1, kN);

    bf16x8 a[8], bfr[4];
#pragma unroll
    for (int m = 0; m < 8; ++m)
      a[m] = *(const bf16x8*)&Als[c][(wr * 128 + m * 16 + rrow) * 32 + kofs];
#pragma unroll
    for (int n = 0; n < 4; ++n)
      bfr[n] = *(const bf16x8*)&Bls[c][(wc * 64 + n * 16 + rrow) * 32 + kofs];

    __builtin_amdgcn_s_setprio(1);
#pragma unroll
    for (int m = 0; m < 8; ++m)
#pragma unroll
      for (int n = 0; n < 4; ++n)
        acc[m][n] = __builtin_amdgcn_mfma_f32_16x16x32_bf16(a[m], bfr[n], acc[m][n], 0, 0, 0);
    __builtin_amdgcn_s_setprio(0);

    VMCNT(0);
    BARRIER();
  }

  float* pp = part + (size_t)sp * NTOK * HDIM;
#pragma unroll
  for (int m = 0; m < 8; ++m) {
#pragma unroll
    for (int n = 0; n < 4; ++n) {
      const int col = col0 + wc * 64 + n * 16 + rrow;
#pragma unroll
      for (int r = 0; r < 4; ++r) {
        const int row = row0 + wr * 128 + m * 16 + klane * 4 + r;
        pp[(size_t)row * HDIM + col] = acc[m][n][r];
      }
    }
  }
}

// ---------------- reduce: out = sum_{e} partial_e + sum_e rw*down_bias ----------------
__global__ __launch_bounds__(256) void k_reduce(const float* __restrict__ part,
                                                const float* __restrict__ dbias,
                                                const float* __restrict__ rw,
                                                float* __restrict__ out) {
  const int i = blockIdx.x * 256 + threadIdx.x;
  const int i4 = i * 4;
  const int n = i4 >> 11;
  const int h = i4 & 2047;
  const size_t MSZ = (size_t)NTOK * HDIM / 4;
  const float4* p = (const float4*)part;
  float4 s = {0.f, 0.f, 0.f, 0.f};
#pragma unroll
  for (int sp = 0; sp < NEXP; ++sp) {
    float4 v = p[i + (size_t)sp * MSZ];
    s.x += v.x; s.y += v.y; s.z += v.z; s.w += v.w;
  }
#pragma unroll
  for (int e = 0; e < NEXP; ++e) {
    float rwe = rw[n * NEXP + e];
    float4 db = *(const float4*)&dbias[(size_t)e * HDIM + h];
    s.x += rwe * db.x; s.y += rwe * db.y;
    s.z += rwe * db.z; s.w += rwe * db.w;
  }
  *(float4*)&out[i4] = s;
}

extern "C" void kernel_launch(void* const* d_in, const int* in_sizes, int n_in,
                              void* d_out, int out_size, void* d_ws, size_t ws_size,
                              hipStream_t stream) {
  const float* hs   = (const float*)d_in[0];
  const float* rw   = (const float*)d_in[1];
  const float* gup  = (const float*)d_in[2];
  const float* gupb = (const float*)d_in[3];
  const float* dwn  = (const float*)d_in[4];
  const float* dwnb = (const float*)d_in[5];
  float* out = (float*)d_out;

  u16* xbf   = (u16*)d_ws;
  u16* w1t   = xbf + (size_t)NTOK * HDIM;
  u16* w2t   = w1t + (size_t)NEXP * I2 * HDIM;
  u16* inter = w2t + (size_t)NEXP * HDIM * IDIM;
  float* part = (float*)w1t;    // 8 x 16MB fp32 partials = 128MB = w1t region exactly
  size_t need = ((size_t)NTOK * HDIM + (size_t)NEXP * I2 * HDIM +
                 (size_t)NEXP * HDIM * IDIM + (size_t)NEXP * NTOK * IDIM) * 2;
  if (ws_size < need) return;

  k_cvt<<<(NTOK * HDIM) / (256 * 8), 256, 0, stream>>>(hs, xbf);

  dim3 g1(I2 / 32, HDIM / 32, NEXP);
  k_tc<<<g1, 256, 0, stream>>>(gup, w1t, HDIM, I2);
  dim3 g2(HDIM / 32, IDIM / 32, NEXP);
  k_tc<<<g2, 256, 0, stream>>>(dwn, w2t, IDIM, HDIM);

  k_gemm1<<<dim3(1024), 512, 0, stream>>>(xbf, w1t, gupb, rw, inter);

  k_gemm2<<<dim3(512), 512, 0, stream>>>(inter, w2t, part);

  k_reduce<<<dim3(NTOK * HDIM / 1024), 256, 0, stream>>>(part, dwnb, rw, out);
}

// Round 10
// 723.105 us; speedup vs baseline: 5.2971x; 5.2971x over previous
//
#include <hip/hip_runtime.h>
#include <cstdint>
#include <cstddef>

#define ALPHA 1.702f
#define LIMIT 7.0f

#define NTOK 2048
#define HDIM 2048
#define IDIM 2048
#define I2   4096
#define NEXP 8

typedef float f32x4 __attribute__((ext_vector_type(4)));
typedef short bf16x8 __attribute__((ext_vector_type(8)));
typedef unsigned short u16;

__device__ __forceinline__ u16 f2bf(float f) {
  unsigned u = __float_as_uint(f);
  u += 0x7fffu + ((u >> 16) & 1u);   // RNE
  return (u16)(u >> 16);
}

__device__ __forceinline__ void gload_lds16(const void* g, void* l) {
  __builtin_amdgcn_global_load_lds(
      (const __attribute__((address_space(1))) void*)g,
      (__attribute__((address_space(3))) void*)l, 16, 0, 0);
}

#define BARRIER() do { asm volatile("" ::: "memory"); __builtin_amdgcn_s_barrier(); asm volatile("" ::: "memory"); } while (0)
#define VMCNT(n)  asm volatile("s_waitcnt vmcnt(" #n ")" ::: "memory")

// ---------------- x: fp32 -> bf16 ----------------
__global__ __launch_bounds__(256) void k_cvt(const float* __restrict__ in,
                                             u16* __restrict__ out) {
  int i = blockIdx.x * blockDim.x + threadIdx.x;
  const float4* p = (const float4*)in + (size_t)i * 2;
  float4 a = p[0], b = p[1];
  union { u16 s[8]; uint4 v; } o;
  o.s[0] = f2bf(a.x); o.s[1] = f2bf(a.y); o.s[2] = f2bf(a.z); o.s[3] = f2bf(a.w);
  o.s[4] = f2bf(b.x); o.s[5] = f2bf(b.y); o.s[6] = f2bf(b.z); o.s[7] = f2bf(b.w);
  ((uint4*)out)[i] = o.v;
}

// ------------- transpose + convert: (R,C) fp32 -> (C,R) bf16 (verified 32x32) -------------
__global__ __launch_bounds__(256) void k_tc(const float* __restrict__ in,
                                            u16* __restrict__ out, int R, int C) {
  __shared__ float tile[32][33];
  const size_t mo = (size_t)blockIdx.z * R * C;
  const float* ip = in + mo;
  u16* op = out + mo;
  int c0 = blockIdx.x * 32, r0 = blockIdx.y * 32;
  int t = threadIdx.x;
  int tr = t >> 3, tc = (t & 7) * 4;
  float4 v = *(const float4*)&ip[(size_t)(r0 + tr) * C + c0 + tc];
  tile[tr][tc] = v.x; tile[tr][tc + 1] = v.y;
  tile[tr][tc + 2] = v.z; tile[tr][tc + 3] = v.w;
  __syncthreads();
  ushort4 o;
  o.x = f2bf(tile[tc + 0][tr]);
  o.y = f2bf(tile[tc + 1][tr]);
  o.z = f2bf(tile[tc + 2][tr]);
  o.w = f2bf(tile[tc + 3][tr]);
  *(ushort4*)&op[(size_t)(c0 + tr) * R + r0 + tc] = o;
}

// ========== 256x256 8-wave GEMM core: BK=32, ring-3 LDS (96KB), 1 barrier/K-tile ==========
// Stage tile t+2 FIRST (issue-early), 12 ds_read + 32 MFMA, VMCNT(4) (t+1 landed,
// t+2 stays in flight), BARRIER. 2-tile prefetch depth covers ~900cyc HBM latency.
// Swizzle (r9-verified): LDS[r][slot s] holds global k-slot s ^ ((r>>1)&3).

// ---------------- GEMM1: gate_up + activation + rw fold ----------------
__global__ __launch_bounds__(512, 2) void k_gemm1(const u16* __restrict__ xbf,
                                                  const u16* __restrict__ w1t,
                                                  const float* __restrict__ gub,
                                                  const float* __restrict__ rw,
                                                  u16* __restrict__ inter) {
  __shared__ __align__(16) u16 Als[3][256 * 32];
  __shared__ __align__(16) u16 Bls[3][256 * 32];

  const int bid = (int)blockIdx.x;
  const int L = (bid & 7) * 128 + (bid >> 3);
  const int mtile = L & 7, ntile = (L >> 3) & 15, e = L >> 7;
  const int row0 = mtile * 256, col0 = ntile * 256;
  const u16* A = xbf;
  const u16* B = w1t + (size_t)e * I2 * HDIM;

  const int tid = threadIdx.x;
  const int w = tid >> 6, lane = tid & 63;
  const int wr = w >> 2, wc = w & 3;
  const int rrow = lane & 15, klane = lane >> 4;
  const int kofs = ((klane ^ ((rrow >> 1) & 3)) << 3);

  auto stA = [&](int buf, int k0) {
#pragma unroll
    for (int j = 0; j < 2; ++j) {
      int c = (w * 2 + j) * 64 + lane;
      int r = c >> 2, g = c & 3;
      int ks = ((g ^ ((r >> 1) & 3)) << 3);
      gload_lds16(A + (size_t)(row0 + r) * HDIM + k0 + ks,
                  &Als[buf][(size_t)(w * 2 + j) * 512]);
    }
  };
  auto stB = [&](int buf, int k0) {
#pragma unroll
    for (int j = 0; j < 2; ++j) {
      int c = (w * 2 + j) * 64 + lane;
      int r = c >> 2, g = c & 3;
      int ks = ((g ^ ((r >> 1) & 3)) << 3);
      gload_lds16(B + (size_t)(col0 + r) * HDIM + k0 + ks,
                  &Bls[buf][(size_t)(w * 2 + j) * 512]);
    }
  };

  f32x4 acc[8][4];
#pragma unroll
  for (int i = 0; i < 8; ++i)
#pragma unroll
    for (int j = 0; j < 4; ++j) acc[i][j] = (f32x4){0.f, 0.f, 0.f, 0.f};

  // prologue: tiles 0,1 -> bufs 0,1
  stA(0, 0); stB(0, 0);
  stA(1, 32); stB(1, 32);
  VMCNT(4);            // tile0 landed; tile1 in flight
  BARRIER();

  for (int t = 0; t < 64; ++t) {
    const int cur = t % 3;
    const int nb = (t + 2) % 3;
    const int kN = (t + 2 < 64 ? t + 2 : 63) * 32;
    stA(nb, kN); stB(nb, kN);          // issue-early; readers closed at t-1's barrier

    bf16x8 a[8], bfr[4];
#pragma unroll
    for (int m = 0; m < 8; ++m)
      a[m] = *(const bf16x8*)&Als[cur][(wr * 128 + m * 16 + rrow) * 32 + kofs];
#pragma unroll
    for (int n = 0; n < 4; ++n)
      bfr[n] = *(const bf16x8*)&Bls[cur][(wc * 64 + n * 16 + rrow) * 32 + kofs];

    __builtin_amdgcn_s_setprio(1);
#pragma unroll
    for (int m = 0; m < 8; ++m)
#pragma unroll
      for (int n = 0; n < 4; ++n)
        acc[m][n] = __builtin_amdgcn_mfma_f32_16x16x32_bf16(a[m], bfr[n], acc[m][n], 0, 0, 0);
    __builtin_amdgcn_s_setprio(0);

    VMCNT(4);          // tile t+1 landed for next iter; t+2's 4 stay in flight
    BARRIER();
  }

  const float* bias = gub + (size_t)e * I2;
  u16* ip = inter + (size_t)e * NTOK * IDIM;
#pragma unroll
  for (int m = 0; m < 8; ++m) {
#pragma unroll
    for (int n = 0; n < 4; ++n) {
      const int col = col0 + wc * 64 + n * 16 + rrow;
      const float bv = bias[col];
#pragma unroll
      for (int r = 0; r < 4; ++r) {
        const int row = row0 + wr * 128 + m * 16 + klane * 4 + r;
        float gu = acc[m][n][r] + bv;
        float pg = __shfl_xor(gu, 1);
        float gate = (lane & 1) ? pg : gu;
        float up   = (lane & 1) ? gu : pg;
        gate = fminf(gate, LIMIT);
        up = fminf(fmaxf(up, -LIMIT), LIMIT);
        float glu = gate / (1.f + __expf(-ALPHA * gate));
        float val = (up + 1.f) * glu * rw[row * NEXP + e];
        if (!(lane & 1)) ip[(size_t)row * IDIM + (col >> 1)] = f2bf(val);
      }
    }
  }
}

// ---------------- GEMM2: ring-3 core, split-K=4 (2 experts per split), grid 256 ----------------
__global__ __launch_bounds__(512, 2) void k_gemm2(const u16* __restrict__ inter,
                                                  const u16* __restrict__ w2t,
                                                  float* __restrict__ part) {
  __shared__ __align__(16) u16 Als[3][256 * 32];
  __shared__ __align__(16) u16 Bls[3][256 * 32];

  const int bid = (int)blockIdx.x;
  const int L = (bid & 7) * 32 + (bid >> 3);
  const int mtile = L & 7, ntile = (L >> 3) & 7, sp = L >> 6;
  const int row0 = mtile * 256, col0 = ntile * 256;
  const int es = sp * 2;

  const int tid = threadIdx.x;
  const int w = tid >> 6, lane = tid & 63;
  const int wr = w >> 2, wc = w & 3;
  const int rrow = lane & 15, klane = lane >> 4;
  const int kofs = ((klane ^ ((rrow >> 1) & 3)) << 3);

  // k0 in [0,4096): expert = es + (k0>>11), intra-expert k = k0 & 2047 (BK=32 never straddles)
  auto stA = [&](int buf, int k0) {
    const u16* Ab = inter + (size_t)(es + (k0 >> 11)) * NTOK * IDIM;
    const int kk = k0 & 2047;
#pragma unroll
    for (int j = 0; j < 2; ++j) {
      int c = (w * 2 + j) * 64 + lane;
      int r = c >> 2, g = c & 3;
      int ks = ((g ^ ((r >> 1) & 3)) << 3);
      gload_lds16(Ab + (size_t)(row0 + r) * IDIM + kk + ks,
                  &Als[buf][(size_t)(w * 2 + j) * 512]);
    }
  };
  auto stB = [&](int buf, int k0) {
    const u16* Bb = w2t + (size_t)(es + (k0 >> 11)) * HDIM * IDIM;
    const int kk = k0 & 2047;
#pragma unroll
    for (int j = 0; j < 2; ++j) {
      int c = (w * 2 + j) * 64 + lane;
      int r = c >> 2, g = c & 3;
      int ks = ((g ^ ((r >> 1) & 3)) << 3);
      gload_lds16(Bb + (size_t)(col0 + r) * IDIM + kk + ks,
                  &Bls[buf][(size_t)(w * 2 + j) * 512]);
    }
  };

  f32x4 acc[8][4];
#pragma unroll
  for (int i = 0; i < 8; ++i)
#pragma unroll
    for (int j = 0; j < 4; ++j) acc[i][j] = (f32x4){0.f, 0.f, 0.f, 0.f};

  stA(0, 0); stB(0, 0);
  stA(1, 32); stB(1, 32);
  VMCNT(4);
  BARRIER();

  for (int t = 0; t < 128; ++t) {      // K=4096, 128 tiles of 32
    const int cur = t % 3;
    const int nb = (t + 2) % 3;
    const int kN = (t + 2 < 128 ? t + 2 : 127) * 32;
    stA(nb, kN); stB(nb, kN);

    bf16x8 a[8], bfr[4];
#pragma unroll
    for (int m = 0; m < 8; ++m)
      a[m] = *(const bf16x8*)&Als[cur][(wr * 128 + m * 16 + rrow) * 32 + kofs];
#pragma unroll
    for (int n = 0; n < 4; ++n)
      bfr[n] = *(const bf16x8*)&Bls[cur][(wc * 64 + n * 16 + rrow) * 32 + kofs];

    __builtin_amdgcn_s_setprio(1);
#pragma unroll
    for (int m = 0; m < 8; ++m)
#pragma unroll
      for (int n = 0; n < 4; ++n)
        acc[m][n] = __builtin_amdgcn_mfma_f32_16x16x32_bf16(a[m], bfr[n], acc[m][n], 0, 0, 0);
    __builtin_amdgcn_s_setprio(0);

    VMCNT(4);
    BARRIER();
  }

  float* pp = part + (size_t)sp * NTOK * HDIM;
#pragma unroll
  for (int m = 0; m < 8; ++m) {
#pragma unroll
    for (int n = 0; n < 4; ++n) {
      const int col = col0 + wc * 64 + n * 16 + rrow;
#pragma unroll
      for (int r = 0; r < 4; ++r) {
        const int row = row0 + wr * 128 + m * 16 + klane * 4 + r;
        pp[(size_t)row * HDIM + col] = acc[m][n][r];
      }
    }
  }
}

// ---------------- reduce: out = sum_splits partial + sum_e rw*down_bias ----------------
__global__ __launch_bounds__(256) void k_reduce(const float* __restrict__ part,
                                                const float* __restrict__ dbias,
                                                const float* __restrict__ rw,
                                                float* __restrict__ out) {
  const int i = blockIdx.x * 256 + threadIdx.x;
  const int i4 = i * 4;
  const int n = i4 >> 11;
  const int h = i4 & 2047;
  const size_t MSZ = (size_t)NTOK * HDIM / 4;
  const float4* p = (const float4*)part;
  float4 v0 = p[i];
  float4 v1 = p[i + MSZ];
  float4 v2 = p[i + 2 * MSZ];
  float4 v3 = p[i + 3 * MSZ];
  float4 s;
  s.x = (v0.x + v1.x) + (v2.x + v3.x);
  s.y = (v0.y + v1.y) + (v2.y + v3.y);
  s.z = (v0.z + v1.z) + (v2.z + v3.z);
  s.w = (v0.w + v1.w) + (v2.w + v3.w);
#pragma unroll
  for (int e = 0; e < NEXP; ++e) {
    float rwe = rw[n * NEXP + e];
    float4 db = *(const float4*)&dbias[(size_t)e * HDIM + h];
    s.x += rwe * db.x; s.y += rwe * db.y;
    s.z += rwe * db.z; s.w += rwe * db.w;
  }
  *(float4*)&out[i4] = s;
}

extern "C" void kernel_launch(void* const* d_in, const int* in_sizes, int n_in,
                              void* d_out, int out_size, void* d_ws, size_t ws_size,
                              hipStream_t stream) {
  const float* hs   = (const float*)d_in[0];
  const float* rw   = (const float*)d_in[1];
  const float* gup  = (const float*)d_in[2];
  const float* gupb = (const float*)d_in[3];
  const float* dwn  = (const float*)d_in[4];
  const float* dwnb = (const float*)d_in[5];
  float* out = (float*)d_out;

  u16* xbf   = (u16*)d_ws;
  u16* w1t   = xbf + (size_t)NTOK * HDIM;
  u16* w2t   = w1t + (size_t)NEXP * I2 * HDIM;
  u16* inter = w2t + (size_t)NEXP * HDIM * IDIM;
  float* part = (float*)w1t;   // 4 x 16MB fp32 partials in dead w1t region
  size_t need = ((size_t)NTOK * HDIM + (size_t)NEXP * I2 * HDIM +
                 (size_t)NEXP * HDIM * IDIM + (size_t)NEXP * NTOK * IDIM) * 2;
  if (ws_size < need) return;

  k_cvt<<<(NTOK * HDIM) / (256 * 8), 256, 0, stream>>>(hs, xbf);

  dim3 g1(I2 / 32, HDIM / 32, NEXP);
  k_tc<<<g1, 256, 0, stream>>>(gup, w1t, HDIM, I2);
  dim3 g2(HDIM / 32, IDIM / 32, NEXP);
  k_tc<<<g2, 256, 0, stream>>>(dwn, w2t, IDIM, HDIM);

  k_gemm1<<<dim3(1024), 512, 0, stream>>>(xbf, w1t, gupb, rw, inter);

  k_gemm2<<<dim3(256), 512, 0, stream>>>(inter, w2t, part);

  k_reduce<<<dim3(NTOK * HDIM / 1024), 256, 0, stream>>>(part, dwnb, rw, out);
}

// Round 11
// 611.513 us; speedup vs baseline: 6.2637x; 1.1825x over previous
//
#include <hip/hip_runtime.h>
#include <cstdint>
#include <cstddef>

#define ALPHA 1.702f
#define LIMIT 7.0f

#define NTOK 2048
#define HDIM 2048
#define IDIM 2048
#define I2   4096
#define NEXP 8

typedef float f32x4 __attribute__((ext_vector_type(4)));
typedef float f32x16 __attribute__((ext_vector_type(16)));
typedef short bf16x8 __attribute__((ext_vector_type(8)));
typedef unsigned short u16;

__device__ __forceinline__ u16 f2bf(float f) {
  unsigned u = __float_as_uint(f);
  u += 0x7fffu + ((u >> 16) & 1u);   // RNE
  return (u16)(u >> 16);
}

__device__ __forceinline__ void gload_lds16(const void* g, void* l) {
  __builtin_amdgcn_global_load_lds(
      (const __attribute__((address_space(1))) void*)g,
      (__attribute__((address_space(3))) void*)l, 16, 0, 0);
}

#define BARRIER() do { asm volatile("" ::: "memory"); __builtin_amdgcn_s_barrier(); asm volatile("" ::: "memory"); } while (0)
#define VMCNT(n)  asm volatile("s_waitcnt vmcnt(" #n ")" ::: "memory")

// ---------------- x: fp32 -> bf16 ----------------
__global__ __launch_bounds__(256) void k_cvt(const float* __restrict__ in,
                                             u16* __restrict__ out) {
  int i = blockIdx.x * blockDim.x + threadIdx.x;
  const float4* p = (const float4*)in + (size_t)i * 2;
  float4 a = p[0], b = p[1];
  union { u16 s[8]; uint4 v; } o;
  o.s[0] = f2bf(a.x); o.s[1] = f2bf(a.y); o.s[2] = f2bf(a.z); o.s[3] = f2bf(a.w);
  o.s[4] = f2bf(b.x); o.s[5] = f2bf(b.y); o.s[6] = f2bf(b.z); o.s[7] = f2bf(b.w);
  ((uint4*)out)[i] = o.v;
}

// ------------- transpose + convert: (R,C) fp32 -> (C,R) bf16 (verified 32x32) -------------
__global__ __launch_bounds__(256) void k_tc(const float* __restrict__ in,
                                            u16* __restrict__ out, int R, int C) {
  __shared__ float tile[32][33];
  const size_t mo = (size_t)blockIdx.z * R * C;
  const float* ip = in + mo;
  u16* op = out + mo;
  int c0 = blockIdx.x * 32, r0 = blockIdx.y * 32;
  int t = threadIdx.x;
  int tr = t >> 3, tc = (t & 7) * 4;
  float4 v = *(const float4*)&ip[(size_t)(r0 + tr) * C + c0 + tc];
  tile[tr][tc] = v.x; tile[tr][tc + 1] = v.y;
  tile[tr][tc + 2] = v.z; tile[tr][tc + 3] = v.w;
  __syncthreads();
  ushort4 o;
  o.x = f2bf(tile[tc + 0][tr]);
  o.y = f2bf(tile[tc + 1][tr]);
  o.z = f2bf(tile[tc + 2][tr]);
  o.w = f2bf(tile[tc + 3][tr]);
  *(ushort4*)&op[(size_t)(c0 + tr) * R + r0 + tc] = o;
}

// ============ 256x256 8-wave 8-phase GEMM core, 32x32x16 MFMA (r5 skeleton) ============
// acc[mf 0..3][nf 0..1] f32x16. C/D map: col=lane&31, row=(reg&3)+8*(reg>>2)+4*(lane>>5).
// MQ32(mh,nh,bb): quadrant = mfr {mh*2, mh*2+1} x nfr nh, full BK=64 (4 ks of 16).
#define MQ32(mh, nh, bb) \
  _Pragma("unroll") for (int mf2 = 0; mf2 < 2; ++mf2) \
  _Pragma("unroll") for (int ks = 0; ks < 4; ++ks) \
    acc[(mh)*2+mf2][nh] = __builtin_amdgcn_mfma_f32_32x32x16_bf16( \
        a32[mf2][ks], (bb)[ks], acc[(mh)*2+mf2][nh], 0, 0, 0);

// ---------------- GEMM1: gate_up + activation + rw fold ----------------
__global__ __launch_bounds__(512, 2) void k_gemm1(const u16* __restrict__ xbf,
                                                  const u16* __restrict__ w1t,
                                                  const float* __restrict__ gub,
                                                  const float* __restrict__ rw,
                                                  u16* __restrict__ inter) {
  __shared__ __align__(16) u16 Als[4][128 * 64];
  __shared__ __align__(16) u16 Bls[4][128 * 64];

  const int bid = (int)blockIdx.x;
  const int L = (bid & 7) * 128 + (bid >> 3);
  const int mtile = L & 7, ntile = (L >> 3) & 15, e = L >> 7;
  const int row0 = mtile * 256, col0 = ntile * 256;
  const u16* A = xbf;
  const u16* B = w1t + (size_t)e * I2 * HDIM;

  const int tid = threadIdx.x;
  const int w = tid >> 6, lane = tid & 63;
  const int wr = w >> 2, wc = w & 3;
  const int l31 = lane & 31, hi = lane >> 5;

  auto stA = [&](int reg, int h, int k0) {
#pragma unroll
    for (int j = 0; j < 2; ++j) {
      int c = (w * 2 + j) * 64 + lane;
      int r = c >> 3, gg = c & 7;
      int ksw = ((gg ^ (r & 7)) << 3);
      int R = ((r >> 6) << 7) + h * 64 + (r & 63);
      gload_lds16(A + (size_t)(row0 + R) * HDIM + k0 + ksw,
                  &Als[reg][(size_t)(w * 2 + j) * 512]);
    }
  };
  auto stB = [&](int reg, int h, int k0) {
#pragma unroll
    for (int j = 0; j < 2; ++j) {
      int c = (w * 2 + j) * 64 + lane;
      int r = c >> 3, gg = c & 7;
      int ksw = ((gg ^ (r & 7)) << 3);
      int C = ((r >> 5) << 6) + h * 32 + (r & 31);
      gload_lds16(B + (size_t)(col0 + C) * HDIM + k0 + ksw,
                  &Bls[reg][(size_t)(w * 2 + j) * 512]);
    }
  };

  f32x16 acc[4][2];
#pragma unroll
  for (int i = 0; i < 4; ++i)
#pragma unroll
    for (int j = 0; j < 2; ++j)
#pragma unroll
      for (int q = 0; q < 16; ++q) acc[i][j][q] = 0.f;

  bf16x8 a32[2][4], b0[4], b1[4];
  // rdA: region reg holds A-half h for this buf; frags mf2 0..1 (global mfr = h*2+mf2)
  auto rdA = [&](int reg) {
#pragma unroll
    for (int mf2 = 0; mf2 < 2; ++mf2) {
      const int q = wr * 64 + mf2 * 32 + l31;
#pragma unroll
      for (int ks = 0; ks < 4; ++ks)
        a32[mf2][ks] = *(const bf16x8*)&Als[reg][q * 64 + (((ks * 2 + hi) ^ (q & 7)) << 3)];
    }
  };
  auto rdB0 = [&](int reg) {
    const int q = wc * 32 + l31;
#pragma unroll
    for (int ks = 0; ks < 4; ++ks)
      b0[ks] = *(const bf16x8*)&Bls[reg][q * 64 + (((ks * 2 + hi) ^ (q & 7)) << 3)];
  };
  auto rdB1 = [&](int reg) {
    const int q = wc * 32 + l31;
#pragma unroll
    for (int ks = 0; ks < 4; ++ks)
      b1[ks] = *(const bf16x8*)&Bls[reg][q * 64 + (((ks * 2 + hi) ^ (q & 7)) << 3)];
  };

  stB(0, 0, 0); stB(1, 1, 0); stA(0, 0, 0); stA(1, 1, 0);
  stB(2, 0, 64); stB(3, 1, 64); stA(2, 0, 64);
  VMCNT(8);
  BARRIER();

  for (int i = 0; i < 16; ++i) {
    const int t = 2 * i;
    const int kA1 = (t + 1) * 64;
    const int kN0 = (t + 2 < 32 ? t + 2 : 31) * 64;
    const int kN1 = (t + 3 < 32 ? t + 3 : 31) * 64;

    rdA(0); rdB0(0);
    stA(3, 1, kA1);
    BARRIER();
    __builtin_amdgcn_s_setprio(1); MQ32(0, 0, b0); __builtin_amdgcn_s_setprio(0);
    BARRIER();

    rdB1(1);
    stB(0, 0, kN0);
    BARRIER();
    __builtin_amdgcn_s_setprio(1); MQ32(0, 1, b1); __builtin_amdgcn_s_setprio(0);
    VMCNT(10);
    BARRIER();

    rdA(1);
    stB(1, 1, kN0);
    BARRIER();
    __builtin_amdgcn_s_setprio(1); MQ32(1, 0, b0); __builtin_amdgcn_s_setprio(0);
    BARRIER();

    stA(0, 0, kN0);
    BARRIER();
    __builtin_amdgcn_s_setprio(1); MQ32(1, 1, b1); __builtin_amdgcn_s_setprio(0);
    VMCNT(8);
    BARRIER();

    rdA(2); rdB0(2);
    stA(1, 1, kN0);
    BARRIER();
    __builtin_amdgcn_s_setprio(1); MQ32(0, 0, b0); __builtin_amdgcn_s_setprio(0);
    BARRIER();

    rdB1(3);
    stB(2, 0, kN1);
    BARRIER();
    __builtin_amdgcn_s_setprio(1); MQ32(0, 1, b1); __builtin_amdgcn_s_setprio(0);
    VMCNT(10);
    BARRIER();

    rdA(3);
    stB(3, 1, kN1);
    BARRIER();
    __builtin_amdgcn_s_setprio(1); MQ32(1, 0, b0); __builtin_amdgcn_s_setprio(0);
    BARRIER();

    stA(2, 0, kN1);
    BARRIER();
    __builtin_amdgcn_s_setprio(1); MQ32(1, 1, b1); __builtin_amdgcn_s_setprio(0);
    VMCNT(8);
    BARRIER();
  }

  // epilogue: 32x32 C-map; col parity = lane parity -> shfl_xor(1) pairs gate/up
  const float* bias = gub + (size_t)e * I2;
  u16* ip = inter + (size_t)e * NTOK * IDIM;
#pragma unroll
  for (int mf = 0; mf < 4; ++mf) {
#pragma unroll
    for (int nf = 0; nf < 2; ++nf) {
      const int col = col0 + wc * 64 + nf * 32 + l31;
      const float bv = bias[col];
#pragma unroll
      for (int reg = 0; reg < 16; ++reg) {
        const int row = row0 + wr * 128 + mf * 32 + (reg & 3) + 8 * (reg >> 2) + 4 * hi;
        float gu = acc[mf][nf][reg] + bv;
        float pg = __shfl_xor(gu, 1);
        float gate = (lane & 1) ? pg : gu;
        float up   = (lane & 1) ? gu : pg;
        gate = fminf(gate, LIMIT);
        up = fminf(fmaxf(up, -LIMIT), LIMIT);
        float glu = gate / (1.f + __expf(-ALPHA * gate));
        float val = (up + 1.f) * glu * rw[row * NEXP + e];
        if (!(lane & 1)) ip[(size_t)row * IDIM + (col >> 1)] = f2bf(val);
      }
    }
  }
}

// ---------------- GEMM2: same core, split-K=4 (2 experts per split) ----------------
__global__ __launch_bounds__(512, 2) void k_gemm2(const u16* __restrict__ inter,
                                                  const u16* __restrict__ w2t,
                                                  float* __restrict__ part) {
  __shared__ __align__(16) u16 Als[4][128 * 64];
  __shared__ __align__(16) u16 Bls[4][128 * 64];

  const int bid = (int)blockIdx.x;
  const int L = (bid & 7) * 32 + (bid >> 3);
  const int mtile = L & 7, ntile = (L >> 3) & 7, sp = L >> 6;
  const int row0 = mtile * 256, col0 = ntile * 256;
  const int es = sp * 2;

  const int tid = threadIdx.x;
  const int w = tid >> 6, lane = tid & 63;
  const int wr = w >> 2, wc = w & 3;
  const int l31 = lane & 31, hi = lane >> 5;

  auto stA = [&](int reg, int h, int k0) {
    const u16* Ab = inter + (size_t)(es + (k0 >> 11)) * NTOK * IDIM;
    const int kk = k0 & 2047;
#pragma unroll
    for (int j = 0; j < 2; ++j) {
      int c = (w * 2 + j) * 64 + lane;
      int r = c >> 3, gg = c & 7;
      int ksw = ((gg ^ (r & 7)) << 3);
      int R = ((r >> 6) << 7) + h * 64 + (r & 63);
      gload_lds16(Ab + (size_t)(row0 + R) * IDIM + kk + ksw,
                  &Als[reg][(size_t)(w * 2 + j) * 512]);
    }
  };
  auto stB = [&](int reg, int h, int k0) {
    const u16* Bb = w2t + (size_t)(es + (k0 >> 11)) * HDIM * IDIM;
    const int kk = k0 & 2047;
#pragma unroll
    for (int j = 0; j < 2; ++j) {
      int c = (w * 2 + j) * 64 + lane;
      int r = c >> 3, gg = c & 7;
      int ksw = ((gg ^ (r & 7)) << 3);
      int C = ((r >> 5) << 6) + h * 32 + (r & 31);
      gload_lds16(Bb + (size_t)(col0 + C) * IDIM + kk + ksw,
                  &Bls[reg][(size_t)(w * 2 + j) * 512]);
    }
  };

  f32x16 acc[4][2];
#pragma unroll
  for (int i = 0; i < 4; ++i)
#pragma unroll
    for (int j = 0; j < 2; ++j)
#pragma unroll
      for (int q = 0; q < 16; ++q) acc[i][j][q] = 0.f;

  bf16x8 a32[2][4], b0[4], b1[4];
  auto rdA = [&](int reg) {
#pragma unroll
    for (int mf2 = 0; mf2 < 2; ++mf2) {
      const int q = wr * 64 + mf2 * 32 + l31;
#pragma unroll
      for (int ks = 0; ks < 4; ++ks)
        a32[mf2][ks] = *(const bf16x8*)&Als[reg][q * 64 + (((ks * 2 + hi) ^ (q & 7)) << 3)];
    }
  };
  auto rdB0 = [&](int reg) {
    const int q = wc * 32 + l31;
#pragma unroll
    for (int ks = 0; ks < 4; ++ks)
      b0[ks] = *(const bf16x8*)&Bls[reg][q * 64 + (((ks * 2 + hi) ^ (q & 7)) << 3)];
  };
  auto rdB1 = [&](int reg) {
    const int q = wc * 32 + l31;
#pragma unroll
    for (int ks = 0; ks < 4; ++ks)
      b1[ks] = *(const bf16x8*)&Bls[reg][q * 64 + (((ks * 2 + hi) ^ (q & 7)) << 3)];
  };

  stB(0, 0, 0); stB(1, 1, 0); stA(0, 0, 0); stA(1, 1, 0);
  stB(2, 0, 64); stB(3, 1, 64); stA(2, 0, 64);
  VMCNT(8);
  BARRIER();

  for (int i = 0; i < 32; ++i) {
    const int t = 2 * i;
    const int kA1 = (t + 1) * 64;
    const int kN0 = (t + 2 < 64 ? t + 2 : 63) * 64;
    const int kN1 = (t + 3 < 64 ? t + 3 : 63) * 64;

    rdA(0); rdB0(0);
    stA(3, 1, kA1);
    BARRIER();
    __builtin_amdgcn_s_setprio(1); MQ32(0, 0, b0); __builtin_amdgcn_s_setprio(0);
    BARRIER();

    rdB1(1);
    stB(0, 0, kN0);
    BARRIER();
    __builtin_amdgcn_s_setprio(1); MQ32(0, 1, b1); __builtin_amdgcn_s_setprio(0);
    VMCNT(10);
    BARRIER();

    rdA(1);
    stB(1, 1, kN0);
    BARRIER();
    __builtin_amdgcn_s_setprio(1); MQ32(1, 0, b0); __builtin_amdgcn_s_setprio(0);
    BARRIER();

    stA(0, 0, kN0);
    BARRIER();
    __builtin_amdgcn_s_setprio(1); MQ32(1, 1, b1); __builtin_amdgcn_s_setprio(0);
    VMCNT(8);
    BARRIER();

    rdA(2); rdB0(2);
    stA(1, 1, kN0);
    BARRIER();
    __builtin_amdgcn_s_setprio(1); MQ32(0, 0, b0); __builtin_amdgcn_s_setprio(0);
    BARRIER();

    rdB1(3);
    stB(2, 0, kN1);
    BARRIER();
    __builtin_amdgcn_s_setprio(1); MQ32(0, 1, b1); __builtin_amdgcn_s_setprio(0);
    VMCNT(10);
    BARRIER();

    rdA(3);
    stB(3, 1, kN1);
    BARRIER();
    __builtin_amdgcn_s_setprio(1); MQ32(1, 0, b0); __builtin_amdgcn_s_setprio(0);
    BARRIER();

    stA(2, 0, kN1);
    BARRIER();
    __builtin_amdgcn_s_setprio(1); MQ32(1, 1, b1); __builtin_amdgcn_s_setprio(0);
    VMCNT(8);
    BARRIER();
  }

  float* pp = part + (size_t)sp * NTOK * HDIM;
#pragma unroll
  for (int mf = 0; mf < 4; ++mf) {
#pragma unroll
    for (int nf = 0; nf < 2; ++nf) {
      const int col = col0 + wc * 64 + nf * 32 + l31;
#pragma unroll
      for (int reg = 0; reg < 16; ++reg) {
        const int row = row0 + wr * 128 + mf * 32 + (reg & 3) + 8 * (reg >> 2) + 4 * hi;
        pp[(size_t)row * HDIM + col] = acc[mf][nf][reg];
      }
    }
  }
}

// ---------------- reduce: out = sum_splits partial + sum_e rw*down_bias ----------------
__global__ __launch_bounds__(256) void k_reduce(const float* __restrict__ part,
                                                const float* __restrict__ dbias,
                                                const float* __restrict__ rw,
                                                float* __restrict__ out) {
  const int i = blockIdx.x * 256 + threadIdx.x;
  const int i4 = i * 4;
  const int n = i4 >> 11;
  const int h = i4 & 2047;
  const size_t MSZ = (size_t)NTOK * HDIM / 4;
  const float4* p = (const float4*)part;
  float4 v0 = p[i];
  float4 v1 = p[i + MSZ];
  float4 v2 = p[i + 2 * MSZ];
  float4 v3 = p[i + 3 * MSZ];
  float4 s;
  s.x = (v0.x + v1.x) + (v2.x + v3.x);
  s.y = (v0.y + v1.y) + (v2.y + v3.y);
  s.z = (v0.z + v1.z) + (v2.z + v3.z);
  s.w = (v0.w + v1.w) + (v2.w + v3.w);
#pragma unroll
  for (int e = 0; e < NEXP; ++e) {
    float rwe = rw[n * NEXP + e];
    float4 db = *(const float4*)&dbias[(size_t)e * HDIM + h];
    s.x += rwe * db.x; s.y += rwe * db.y;
    s.z += rwe * db.z; s.w += rwe * db.w;
  }
  *(float4*)&out[i4] = s;
}

extern "C" void kernel_launch(void* const* d_in, const int* in_sizes, int n_in,
                              void* d_out, int out_size, void* d_ws, size_t ws_size,
                              hipStream_t stream) {
  const float* hs   = (const float*)d_in[0];
  const float* rw   = (const float*)d_in[1];
  const float* gup  = (const float*)d_in[2];
  const float* gupb = (const float*)d_in[3];
  const float* dwn  = (const float*)d_in[4];
  const float* dwnb = (const float*)d_in[5];
  float* out = (float*)d_out;

  u16* xbf   = (u16*)d_ws;
  u16* w1t   = xbf + (size_t)NTOK * HDIM;
  u16* w2t   = w1t + (size_t)NEXP * I2 * HDIM;
  u16* inter = w2t + (size_t)NEXP * HDIM * IDIM;
  float* part = (float*)w1t;
  size_t need = ((size_t)NTOK * HDIM + (size_t)NEXP * I2 * HDIM +
                 (size_t)NEXP * HDIM * IDIM + (size_t)NEXP * NTOK * IDIM) * 2;
  if (ws_size < need) return;

  k_cvt<<<(NTOK * HDIM) / (256 * 8), 256, 0, stream>>>(hs, xbf);

  dim3 g1(I2 / 32, HDIM / 32, NEXP);
  k_tc<<<g1, 256, 0, stream>>>(gup, w1t, HDIM, I2);
  dim3 g2(HDIM / 32, IDIM / 32, NEXP);
  k_tc<<<g2, 256, 0, stream>>>(dwn, w2t, IDIM, HDIM);

  k_gemm1<<<dim3(1024), 512, 0, stream>>>(xbf, w1t, gupb, rw, inter);

  k_gemm2<<<dim3(256), 512, 0, stream>>>(inter, w2t, part);

  k_reduce<<<dim3(NTOK * HDIM / 1024), 256, 0, stream>>>(part, dwnb, rw, out);
}

// Round 12
// 558.874 us; speedup vs baseline: 6.8536x; 1.0942x over previous
//
#include <hip/hip_runtime.h>
#include <cstdint>
#include <cstddef>

#define ALPHA 1.702f
#define LIMIT 7.0f

#define NTOK 2048
#define HDIM 2048
#define IDIM 2048
#define I2   4096
#define NEXP 8

typedef float f32x4 __attribute__((ext_vector_type(4)));
typedef short bf16x8 __attribute__((ext_vector_type(8)));
typedef unsigned short u16;

__device__ __forceinline__ u16 f2bf(float f) {
  unsigned u = __float_as_uint(f);
  u += 0x7fffu + ((u >> 16) & 1u);   // RNE
  return (u16)(u >> 16);
}

__device__ __forceinline__ void gload_lds16(const void* g, void* l) {
  __builtin_amdgcn_global_load_lds(
      (const __attribute__((address_space(1))) void*)g,
      (__attribute__((address_space(3))) void*)l, 16, 0, 0);
}

#define BARRIER() do { asm volatile("" ::: "memory"); __builtin_amdgcn_s_barrier(); asm volatile("" ::: "memory"); } while (0)
#define VMCNT(n)  asm volatile("s_waitcnt vmcnt(" #n ")" ::: "memory")

// ---------------- x: fp32 -> bf16 ----------------
__global__ __launch_bounds__(256) void k_cvt(const float* __restrict__ in,
                                             u16* __restrict__ out) {
  int i = blockIdx.x * blockDim.x + threadIdx.x;
  const float4* p = (const float4*)in + (size_t)i * 2;
  float4 a = p[0], b = p[1];
  union { u16 s[8]; uint4 v; } o;
  o.s[0] = f2bf(a.x); o.s[1] = f2bf(a.y); o.s[2] = f2bf(a.z); o.s[3] = f2bf(a.w);
  o.s[4] = f2bf(b.x); o.s[5] = f2bf(b.y); o.s[6] = f2bf(b.z); o.s[7] = f2bf(b.w);
  ((uint4*)out)[i] = o.v;
}

// ------------- transpose + convert: (R,C) fp32 -> (C,R) bf16, 64x64 tiles -------------
// r3's bug was the store reading tile[cc][r+j] (wrong axis); fixed: tile[r+j][cc].
__global__ __launch_bounds__(256) void k_tc(const float* __restrict__ in,
                                            u16* __restrict__ out, int R, int C) {
  __shared__ float tile[64][65];
  const size_t mo = (size_t)blockIdx.z * R * C;
  const float* ip = in + mo;
  u16* op = out + mo;
  const int c0 = blockIdx.x * 64, r0 = blockIdx.y * 64;
  const int t = threadIdx.x;
  const int tr = t >> 4;           // 0..15
  const int tc = (t & 15) * 4;     // 0..60
#pragma unroll
  for (int i = 0; i < 4; ++i) {
    float4 v = *(const float4*)&ip[(size_t)(r0 + tr + i * 16) * C + c0 + tc];
    tile[tr + i * 16][tc] = v.x; tile[tr + i * 16][tc + 1] = v.y;
    tile[tr + i * 16][tc + 2] = v.z; tile[tr + i * 16][tc + 3] = v.w;
  }
  __syncthreads();
  const int cc = t >> 2;           // output row (= original col) 0..63
  const int rb = (t & 3) * 8;      // 0..24
#pragma unroll
  for (int i = 0; i < 2; ++i) {
    int r = rb + i * 32;
    union { u16 s[8]; uint4 v; } o;
#pragma unroll
    for (int j = 0; j < 8; ++j) o.s[j] = f2bf(tile[r + j][cc]);   // FIXED axis
    *(uint4*)&op[(size_t)(c0 + cc) * R + r0 + r] = o.v;
  }
}

// ======================= 256x256 8-wave 8-phase GEMM core (r5-verified) =======================
#define MFMA_Q(mh, nh, bb) \
  _Pragma("unroll") for (int mm = 0; mm < 4; ++mm) \
  _Pragma("unroll") for (int nn = 0; nn < 2; ++nn) \
  _Pragma("unroll") for (int ks = 0; ks < 2; ++ks) \
    acc[(mh)*4+mm][(nh)*2+nn] = __builtin_amdgcn_mfma_f32_16x16x32_bf16( \
        a[mm][ks], (bb)[nn][ks], acc[(mh)*4+mm][(nh)*2+nn], 0, 0, 0);

// ---------------- GEMM1: gate_up + activation + rw fold ----------------
__global__ __launch_bounds__(512, 2) void k_gemm1(const u16* __restrict__ xbf,
                                                  const u16* __restrict__ w1t,
                                                  const float* __restrict__ gub,
                                                  const float* __restrict__ rw,
                                                  u16* __restrict__ inter) {
  __shared__ __align__(16) u16 Als[4][128 * 64];
  __shared__ __align__(16) u16 Bls[4][128 * 64];

  const int bid = (int)blockIdx.x;
  const int L = (bid & 7) * 128 + (bid >> 3);
  const int mtile = L & 7, ntile = (L >> 3) & 15, e = L >> 7;
  const int row0 = mtile * 256, col0 = ntile * 256;
  const u16* A = xbf;
  const u16* B = w1t + (size_t)e * I2 * HDIM;

  const int tid = threadIdx.x;
  const int w = tid >> 6, lane = tid & 63;
  const int wr = w >> 2, wc = w & 3;
  const int rrow = lane & 15, klane = lane >> 4;
  const int sA = (wr * 64 + rrow) * 64;
  const int sB = (wc * 32 + rrow) * 64;
  int kofs[2];
  kofs[0] = ((klane ^ (rrow & 7)) << 3);
  kofs[1] = (((4 + klane) ^ (rrow & 7)) << 3);

  auto stA = [&](int reg, int h, int k0) {
#pragma unroll
    for (int j = 0; j < 2; ++j) {
      int c = (w * 2 + j) * 64 + lane;
      int r = c >> 3, gg = c & 7;
      int ksw = ((gg ^ (r & 7)) << 3);
      int R = ((r >> 6) << 7) + h * 64 + (r & 63);
      gload_lds16(A + (size_t)(row0 + R) * HDIM + k0 + ksw,
                  &Als[reg][(size_t)(w * 2 + j) * 512]);
    }
  };
  auto stB = [&](int reg, int h, int k0) {
#pragma unroll
    for (int j = 0; j < 2; ++j) {
      int c = (w * 2 + j) * 64 + lane;
      int r = c >> 3, gg = c & 7;
      int ksw = ((gg ^ (r & 7)) << 3);
      int C = ((r >> 5) << 6) + h * 32 + (r & 31);
      gload_lds16(B + (size_t)(col0 + C) * HDIM + k0 + ksw,
                  &Bls[reg][(size_t)(w * 2 + j) * 512]);
    }
  };

  f32x4 acc[8][4];
#pragma unroll
  for (int i = 0; i < 8; ++i)
#pragma unroll
    for (int j = 0; j < 4; ++j) acc[i][j] = (f32x4){0.f, 0.f, 0.f, 0.f};

  bf16x8 a[4][2], b0[2][2], b1[2][2];
  auto rdA = [&](int reg) {
#pragma unroll
    for (int mm = 0; mm < 4; ++mm)
#pragma unroll
      for (int ks = 0; ks < 2; ++ks)
        a[mm][ks] = *(const bf16x8*)&Als[reg][sA + mm * 1024 + kofs[ks]];
  };
  auto rdB0 = [&](int reg) {
#pragma unroll
    for (int nn = 0; nn < 2; ++nn)
#pragma unroll
      for (int ks = 0; ks < 2; ++ks)
        b0[nn][ks] = *(const bf16x8*)&Bls[reg][sB + nn * 1024 + kofs[ks]];
  };
  auto rdB1 = [&](int reg) {
#pragma unroll
    for (int nn = 0; nn < 2; ++nn)
#pragma unroll
      for (int ks = 0; ks < 2; ++ks)
        b1[nn][ks] = *(const bf16x8*)&Bls[reg][sB + nn * 1024 + kofs[ks]];
  };

  stB(0, 0, 0); stB(1, 1, 0); stA(0, 0, 0); stA(1, 1, 0);
  stB(2, 0, 64); stB(3, 1, 64); stA(2, 0, 64);
  VMCNT(8);
  BARRIER();

  for (int i = 0; i < 16; ++i) {
    const int t = 2 * i;
    const int kA1 = (t + 1) * 64;
    const int kN0 = (t + 2 < 32 ? t + 2 : 31) * 64;
    const int kN1 = (t + 3 < 32 ? t + 3 : 31) * 64;

    rdA(0); rdB0(0);
    stA(3, 1, kA1);
    BARRIER();
    __builtin_amdgcn_s_setprio(1); MFMA_Q(0, 0, b0); __builtin_amdgcn_s_setprio(0);
    BARRIER();

    rdB1(1);
    stB(0, 0, kN0);
    BARRIER();
    __builtin_amdgcn_s_setprio(1); MFMA_Q(0, 1, b1); __builtin_amdgcn_s_setprio(0);
    VMCNT(10);
    BARRIER();

    rdA(1);
    stB(1, 1, kN0);
    BARRIER();
    __builtin_amdgcn_s_setprio(1); MFMA_Q(1, 0, b0); __builtin_amdgcn_s_setprio(0);
    BARRIER();

    stA(0, 0, kN0);
    BARRIER();
    __builtin_amdgcn_s_setprio(1); MFMA_Q(1, 1, b1); __builtin_amdgcn_s_setprio(0);
    VMCNT(8);
    BARRIER();

    rdA(2); rdB0(2);
    stA(1, 1, kN0);
    BARRIER();
    __builtin_amdgcn_s_setprio(1); MFMA_Q(0, 0, b0); __builtin_amdgcn_s_setprio(0);
    BARRIER();

    rdB1(3);
    stB(2, 0, kN1);
    BARRIER();
    __builtin_amdgcn_s_setprio(1); MFMA_Q(0, 1, b1); __builtin_amdgcn_s_setprio(0);
    VMCNT(10);
    BARRIER();

    rdA(3);
    stB(3, 1, kN1);
    BARRIER();
    __builtin_amdgcn_s_setprio(1); MFMA_Q(1, 0, b0); __builtin_amdgcn_s_setprio(0);
    BARRIER();

    stA(2, 0, kN1);
    BARRIER();
    __builtin_amdgcn_s_setprio(1); MFMA_Q(1, 1, b1); __builtin_amdgcn_s_setprio(0);
    VMCNT(8);
    BARRIER();
  }

  const float* bias = gub + (size_t)e * I2;
  u16* ip = inter + (size_t)e * NTOK * IDIM;
#pragma unroll
  for (int ai = 0; ai < 8; ++ai) {
    const int mh = ai >> 2, mm = ai & 3;
#pragma unroll
    for (int bj = 0; bj < 4; ++bj) {
      const int nh = bj >> 1, nn = bj & 1;
      const int col = col0 + wc * 64 + nh * 32 + nn * 16 + rrow;
      const float bv = bias[col];
#pragma unroll
      for (int r = 0; r < 4; ++r) {
        const int row = row0 + wr * 128 + mh * 64 + mm * 16 + klane * 4 + r;
        float gu = acc[ai][bj][r] + bv;
        float pg = __shfl_xor(gu, 1);
        float gate = (lane & 1) ? pg : gu;
        float up   = (lane & 1) ? gu : pg;
        gate = fminf(gate, LIMIT);
        up = fminf(fmaxf(up, -LIMIT), LIMIT);
        float glu = gate / (1.f + __expf(-ALPHA * gate));
        float val = (up + 1.f) * glu * rw[row * NEXP + e];
        if (!(lane & 1)) ip[(size_t)row * IDIM + (col >> 1)] = f2bf(val);
      }
    }
  }
}

// ---------------- GEMM2: 256x256 8-phase, split-K=4 (2 experts per split) ----------------
__global__ __launch_bounds__(512, 2) void k_gemm2(const u16* __restrict__ inter,
                                                  const u16* __restrict__ w2t,
                                                  float* __restrict__ part) {
  __shared__ __align__(16) u16 Als[4][128 * 64];
  __shared__ __align__(16) u16 Bls[4][128 * 64];

  const int bid = (int)blockIdx.x;
  const int L = (bid & 7) * 32 + (bid >> 3);
  const int mtile = L & 7, ntile = (L >> 3) & 7, sp = L >> 6;
  const int row0 = mtile * 256, col0 = ntile * 256;
  const int es = sp * 2;

  const int tid = threadIdx.x;
  const int w = tid >> 6, lane = tid & 63;
  const int wr = w >> 2, wc = w & 3;
  const int rrow = lane & 15, klane = lane >> 4;
  const int sA = (wr * 64 + rrow) * 64;
  const int sB = (wc * 32 + rrow) * 64;
  int kofs[2];
  kofs[0] = ((klane ^ (rrow & 7)) << 3);
  kofs[1] = (((4 + klane) ^ (rrow & 7)) << 3);

  auto stA = [&](int reg, int h, int k0) {
    const u16* Ab = inter + (size_t)(es + (k0 >> 11)) * NTOK * IDIM;
    const int kk = k0 & 2047;
#pragma unroll
    for (int j = 0; j < 2; ++j) {
      int c = (w * 2 + j) * 64 + lane;
      int r = c >> 3, gg = c & 7;
      int ksw = ((gg ^ (r & 7)) << 3);
      int R = ((r >> 6) << 7) + h * 64 + (r & 63);
      gload_lds16(Ab + (size_t)(row0 + R) * IDIM + kk + ksw,
                  &Als[reg][(size_t)(w * 2 + j) * 512]);
    }
  };
  auto stB = [&](int reg, int h, int k0) {
    const u16* Bb = w2t + (size_t)(es + (k0 >> 11)) * HDIM * IDIM;
    const int kk = k0 & 2047;
#pragma unroll
    for (int j = 0; j < 2; ++j) {
      int c = (w * 2 + j) * 64 + lane;
      int r = c >> 3, gg = c & 7;
      int ksw = ((gg ^ (r & 7)) << 3);
      int C = ((r >> 5) << 6) + h * 32 + (r & 31);
      gload_lds16(Bb + (size_t)(col0 + C) * IDIM + kk + ksw,
                  &Bls[reg][(size_t)(w * 2 + j) * 512]);
    }
  };

  f32x4 acc[8][4];
#pragma unroll
  for (int i = 0; i < 8; ++i)
#pragma unroll
    for (int j = 0; j < 4; ++j) acc[i][j] = (f32x4){0.f, 0.f, 0.f, 0.f};

  bf16x8 a[4][2], b0[2][2], b1[2][2];
  auto rdA = [&](int reg) {
#pragma unroll
    for (int mm = 0; mm < 4; ++mm)
#pragma unroll
      for (int ks = 0; ks < 2; ++ks)
        a[mm][ks] = *(const bf16x8*)&Als[reg][sA + mm * 1024 + kofs[ks]];
  };
  auto rdB0 = [&](int reg) {
#pragma unroll
    for (int nn = 0; nn < 2; ++nn)
#pragma unroll
      for (int ks = 0; ks < 2; ++ks)
        b0[nn][ks] = *(const bf16x8*)&Bls[reg][sB + nn * 1024 + kofs[ks]];
  };
  auto rdB1 = [&](int reg) {
#pragma unroll
    for (int nn = 0; nn < 2; ++nn)
#pragma unroll
      for (int ks = 0; ks < 2; ++ks)
        b1[nn][ks] = *(const bf16x8*)&Bls[reg][sB + nn * 1024 + kofs[ks]];
  };

  stB(0, 0, 0); stB(1, 1, 0); stA(0, 0, 0); stA(1, 1, 0);
  stB(2, 0, 64); stB(3, 1, 64); stA(2, 0, 64);
  VMCNT(8);
  BARRIER();

  for (int i = 0; i < 32; ++i) {
    const int t = 2 * i;
    const int kA1 = (t + 1) * 64;
    const int kN0 = (t + 2 < 64 ? t + 2 : 63) * 64;
    const int kN1 = (t + 3 < 64 ? t + 3 : 63) * 64;

    rdA(0); rdB0(0);
    stA(3, 1, kA1);
    BARRIER();
    __builtin_amdgcn_s_setprio(1); MFMA_Q(0, 0, b0); __builtin_amdgcn_s_setprio(0);
    BARRIER();

    rdB1(1);
    stB(0, 0, kN0);
    BARRIER();
    __builtin_amdgcn_s_setprio(1); MFMA_Q(0, 1, b1); __builtin_amdgcn_s_setprio(0);
    VMCNT(10);
    BARRIER();

    rdA(1);
    stB(1, 1, kN0);
    BARRIER();
    __builtin_amdgcn_s_setprio(1); MFMA_Q(1, 0, b0); __builtin_amdgcn_s_setprio(0);
    BARRIER();

    stA(0, 0, kN0);
    BARRIER();
    __builtin_amdgcn_s_setprio(1); MFMA_Q(1, 1, b1); __builtin_amdgcn_s_setprio(0);
    VMCNT(8);
    BARRIER();

    rdA(2); rdB0(2);
    stA(1, 1, kN0);
    BARRIER();
    __builtin_amdgcn_s_setprio(1); MFMA_Q(0, 0, b0); __builtin_amdgcn_s_setprio(0);
    BARRIER();

    rdB1(3);
    stB(2, 0, kN1);
    BARRIER();
    __builtin_amdgcn_s_setprio(1); MFMA_Q(0, 1, b1); __builtin_amdgcn_s_setprio(0);
    VMCNT(10);
    BARRIER();

    rdA(3);
    stB(3, 1, kN1);
    BARRIER();
    __builtin_amdgcn_s_setprio(1); MFMA_Q(1, 0, b0); __builtin_amdgcn_s_setprio(0);
    BARRIER();

    stA(2, 0, kN1);
    BARRIER();
    __builtin_amdgcn_s_setprio(1); MFMA_Q(1, 1, b1); __builtin_amdgcn_s_setprio(0);
    VMCNT(8);
    BARRIER();
  }

  float* pp = part + (size_t)sp * NTOK * HDIM;
#pragma unroll
  for (int ai = 0; ai < 8; ++ai) {
    const int mh = ai >> 2, mm = ai & 3;
#pragma unroll
    for (int bj = 0; bj < 4; ++bj) {
      const int nh = bj >> 1, nn = bj & 1;
      const int col = col0 + wc * 64 + nh * 32 + nn * 16 + rrow;
#pragma unroll
      for (int r = 0; r < 4; ++r) {
        const int row = row0 + wr * 128 + mh * 64 + mm * 16 + klane * 4 + r;
        pp[(size_t)row * HDIM + col] = acc[ai][bj][r];
      }
    }
  }
}

// ---------------- reduce: out = sum_splits partial + sum_e rw*down_bias ----------------
__global__ __launch_bounds__(256) void k_reduce(const float* __restrict__ part,
                                                const float* __restrict__ dbias,
                                                const float* __restrict__ rw,
                                                float* __restrict__ out) {
  const int i = blockIdx.x * 256 + threadIdx.x;
  const int i4 = i * 4;
  const int n = i4 >> 11;
  const int h = i4 & 2047;
  const size_t MSZ = (size_t)NTOK * HDIM / 4;
  const float4* p = (const float4*)part;
  float4 v0 = p[i];
  float4 v1 = p[i + MSZ];
  float4 v2 = p[i + 2 * MSZ];
  float4 v3 = p[i + 3 * MSZ];
  float4 s;
  s.x = (v0.x + v1.x) + (v2.x + v3.x);
  s.y = (v0.y + v1.y) + (v2.y + v3.y);
  s.z = (v0.z + v1.z) + (v2.z + v3.z);
  s.w = (v0.w + v1.w) + (v2.w + v3.w);
#pragma unroll
  for (int e = 0; e < NEXP; ++e) {
    float rwe = rw[n * NEXP + e];
    float4 db = *(const float4*)&dbias[(size_t)e * HDIM + h];
    s.x += rwe * db.x; s.y += rwe * db.y;
    s.z += rwe * db.z; s.w += rwe * db.w;
  }
  *(float4*)&out[i4] = s;
}

extern "C" void kernel_launch(void* const* d_in, const int* in_sizes, int n_in,
                              void* d_out, int out_size, void* d_ws, size_t ws_size,
                              hipStream_t stream) {
  const float* hs   = (const float*)d_in[0];
  const float* rw   = (const float*)d_in[1];
  const float* gup  = (const float*)d_in[2];
  const float* gupb = (const float*)d_in[3];
  const float* dwn  = (const float*)d_in[4];
  const float* dwnb = (const float*)d_in[5];
  float* out = (float*)d_out;

  u16* xbf   = (u16*)d_ws;
  u16* w1t   = xbf + (size_t)NTOK * HDIM;
  u16* w2t   = w1t + (size_t)NEXP * I2 * HDIM;
  u16* inter = w2t + (size_t)NEXP * HDIM * IDIM;
  float* part = (float*)w1t;
  size_t need = ((size_t)NTOK * HDIM + (size_t)NEXP * I2 * HDIM +
                 (size_t)NEXP * HDIM * IDIM + (size_t)NEXP * NTOK * IDIM) * 2;
  if (ws_size < need) return;

  k_cvt<<<(NTOK * HDIM) / (256 * 8), 256, 0, stream>>>(hs, xbf);

  dim3 g1(I2 / 64, HDIM / 64, NEXP);
  k_tc<<<g1, 256, 0, stream>>>(gup, w1t, HDIM, I2);
  dim3 g2(HDIM / 64, IDIM / 64, NEXP);
  k_tc<<<g2, 256, 0, stream>>>(dwn, w2t, IDIM, HDIM);

  k_gemm1<<<dim3(1024), 512, 0, stream>>>(xbf, w1t, gupb, rw, inter);

  k_gemm2<<<dim3(256), 512, 0, stream>>>(inter, w2t, part);

  k_reduce<<<dim3(NTOK * HDIM / 1024), 256, 0, stream>>>(part, dwnb, rw, out);
}